// Round 1
// baseline (599.023 us; speedup 1.0000x reference)
//
#include <hip/hip_runtime.h>
#include <hip/hip_bf16.h>
#include <math.h>

typedef __bf16 bf16x8 __attribute__((ext_vector_type(8)));
typedef float f32x4 __attribute__((ext_vector_type(4)));
typedef __hip_bfloat16 bf16_t;

#define MFMA_BF16(a, b, c) __builtin_amdgcn_mfma_f32_16x16x32_bf16((a), (b), (c), 0, 0, 0)

// async global->LDS, 16B per lane; LDS dest = wave-uniform base + lane*16
__device__ __forceinline__ void async_copy16(const bf16_t* g, bf16_t* lds_base) {
  __builtin_amdgcn_global_load_lds(
      (const __attribute__((address_space(1))) unsigned int*)g,
      (__attribute__((address_space(3))) unsigned int*)lds_base,
      16, 0, 0);
}

// ---------------- cast f32 -> bf16 (vectorized) ----------------
__global__ void cast_f32_to_bf16(const float* __restrict__ in, bf16_t* __restrict__ out, int n4) {
  int i = blockIdx.x * blockDim.x + threadIdx.x;
  if (i < n4) {
    float4 v = ((const float4*)in)[i];
    union { bf16_t h[4]; ushort4 u; } cv;
    cv.h[0] = __float2bfloat16(v.x);
    cv.h[1] = __float2bfloat16(v.y);
    cv.h[2] = __float2bfloat16(v.z);
    cv.h[3] = __float2bfloat16(v.w);
    ((ushort4*)out)[i] = cv.u;
  }
}

// ---------------- transpose + cast -> bf16 ----------------
// in: [R][C] (batched via blockIdx.z), out: [C][R]
template <typename TIN>
__global__ void transpose_to_bf16(const TIN* __restrict__ in, bf16_t* __restrict__ out,
                                  int R, int C) {
  __shared__ float tile[32][33];
  const size_t boff = (size_t)blockIdx.z * R * C;
  in += boff;
  out += boff;
  const int c0 = blockIdx.x * 32, r0 = blockIdx.y * 32;
  const int tx = threadIdx.x, ty = threadIdx.y;
#pragma unroll
  for (int i = ty; i < 32; i += 8)
    tile[i][tx] = (float)in[(size_t)(r0 + i) * C + c0 + tx];
  __syncthreads();
#pragma unroll
  for (int i = ty; i < 32; i += 8)
    out[(size_t)(c0 + i) * R + r0 + tx] = __float2bfloat16(tile[tx][i]);
}

// ---------------- GEMM: C[M,N] = A[M,K] @ Bt[N,K]^T + bias ----------------
// 128x128 tile, BK=32, 256 threads (4 waves, 2x2 of 64x64), mfma 16x16x32 bf16.
template <typename TOUT>
__global__ __launch_bounds__(256, 2) void gemm_bt(
    const bf16_t* __restrict__ A, const bf16_t* __restrict__ Bt,
    const float* __restrict__ bias, TOUT* __restrict__ C,
    int M, int N, int K) {
  __shared__ alignas(16) bf16_t As[128 * 32];
  __shared__ alignas(16) bf16_t Bs[128 * 32];

  const int tid = threadIdx.x;
  const int w = tid >> 6, lane = tid & 63;
  const int quad = lane >> 4, l16 = lane & 15;
  const int wm = w >> 1, wn = w & 1;
  const int m0 = blockIdx.y * 128, n0 = blockIdx.x * 128;

  f32x4 acc[4][4] = {};

  const int srow = lane >> 2;        // 0..15 within a 16-row chunk
  const int scol = (lane & 3) * 8;   // bf16 col offset (16B chunks)

  for (int k0 = 0; k0 < K; k0 += 32) {
#pragma unroll
    for (int c = 0; c < 2; ++c) {
      const int r = w * 32 + c * 16 + srow;
      async_copy16(A + (size_t)(m0 + r) * K + k0 + scol, &As[(w * 32 + c * 16) * 32]);
      async_copy16(Bt + (size_t)(n0 + r) * K + k0 + scol, &Bs[(w * 32 + c * 16) * 32]);
    }
    __syncthreads();

    bf16x8 af[4], bf[4];
#pragma unroll
    for (int i = 0; i < 4; ++i) {
      af[i] = *(const bf16x8*)&As[(wm * 64 + i * 16 + l16) * 32 + quad * 8];
      bf[i] = *(const bf16x8*)&Bs[(wn * 64 + i * 16 + l16) * 32 + quad * 8];
    }
#pragma unroll
    for (int i = 0; i < 4; ++i)
#pragma unroll
      for (int j = 0; j < 4; ++j)
        acc[i][j] = MFMA_BF16(af[i], bf[j], acc[i][j]);
    __syncthreads();
  }

  // epilogue: C/D layout col=lane&15, row=quad*4+reg
#pragma unroll
  for (int i = 0; i < 4; ++i) {
    const int row = m0 + wm * 64 + i * 16 + quad * 4;
#pragma unroll
    for (int j = 0; j < 4; ++j) {
      const int col = n0 + wn * 64 + j * 16 + l16;
      const float bv = bias[col];
#pragma unroll
      for (int r = 0; r < 4; ++r) {
        const float val = acc[i][j][r] + bv;
        if constexpr (__is_same(TOUT, float)) {
          C[(size_t)(row + r) * N + col] = val;
        } else {
          C[(size_t)(row + r) * N + col] = __float2bfloat16(val);
        }
      }
    }
  }
}

// ---------------- GQA flash attention ----------------
// Q: [B*S][2048] bf16 (head h at cols h*64..h*64+63)
// K: [B*S][512]  bf16 (group g at cols g*64..)
// VT: [B*512][2048] bf16 (row b*512 + g*64 + d, col s)
// O: [B*S][2048] bf16
// grid: (S/128, NH, B), 256 threads. Each wave owns 32 q rows.
__global__ __launch_bounds__(256, 2) void gqa_attn(
    const bf16_t* __restrict__ Q, const bf16_t* __restrict__ Kd,
    const bf16_t* __restrict__ VT, bf16_t* __restrict__ O) {
  constexpr int S = 2048, HID = 2048, KV = 512, HD = 64;
  const int tid = threadIdx.x;
  const int w = tid >> 6, lane = tid & 63;
  const int quad = lane >> 4, l16 = lane & 15;
  const int q0 = blockIdx.x * 128;
  const int h = blockIdx.y;
  const int b = blockIdx.z;
  const int g = h >> 2;  // rep = NH/NG = 4

  __shared__ alignas(16) bf16_t Qs[128 * 64];
  __shared__ alignas(16) bf16_t Ks[64 * 64];
  __shared__ alignas(16) bf16_t VTs[64 * 64];
  __shared__ alignas(16) bf16_t Ps[128 * 64];

  const int rr = lane >> 3;        // 0..7
  const int cc = (lane & 7) * 8;   // bf16 col chunk within 64-wide row

  // stage Q tile once (128 rows x 64 d)
#pragma unroll
  for (int c = 0; c < 4; ++c) {
    const int r = w * 32 + c * 8 + rr;
    async_copy16(Q + (size_t)(b * S + q0 + r) * HID + h * HD + cc, &Qs[(w * 32 + c * 8) * 64]);
  }

  const bf16_t* Kbase = Kd + (size_t)b * S * KV + g * HD;
  const bf16_t* Vbase = VT + (size_t)(b * KV + g * HD) * S;

  float m_i[2][4], l_i[2][4];
  f32x4 oacc[2][4] = {};
#pragma unroll
  for (int mt = 0; mt < 2; ++mt)
#pragma unroll
    for (int r = 0; r < 4; ++r) { m_i[mt][r] = -1e30f; l_i[mt][r] = 0.f; }

  const float c1 = 0.125f * 1.44269504089f;  // scale * log2(e)

  for (int s0 = 0; s0 < S; s0 += 64) {
    __syncthreads();  // previous iter's Ks/VTs reads done (also drains Q loads at iter 0)
#pragma unroll
    for (int c = 0; c < 2; ++c) {
      const int r = w * 16 + c * 8 + rr;
      async_copy16(Kbase + (size_t)(s0 + r) * KV + cc, &Ks[(w * 16 + c * 8) * 64]);
      async_copy16(Vbase + (size_t)r * S + s0 + cc, &VTs[(w * 16 + c * 8) * 64]);
    }
    __syncthreads();  // loads landed

    // ---- QK^T: scores [32q x 64kv] per wave ----
    f32x4 sc[2][4] = {};
#pragma unroll
    for (int ks = 0; ks < 2; ++ks) {
      bf16x8 qf[2], kf[4];
#pragma unroll
      for (int mt = 0; mt < 2; ++mt)
        qf[mt] = *(const bf16x8*)&Qs[(w * 32 + mt * 16 + l16) * 64 + ks * 32 + quad * 8];
#pragma unroll
      for (int nt = 0; nt < 4; ++nt)
        kf[nt] = *(const bf16x8*)&Ks[(nt * 16 + l16) * 64 + ks * 32 + quad * 8];
#pragma unroll
      for (int mt = 0; mt < 2; ++mt)
#pragma unroll
        for (int nt = 0; nt < 4; ++nt)
          sc[mt][nt] = MFMA_BF16(qf[mt], kf[nt], sc[mt][nt]);
    }

    // ---- online softmax (each wave owns its 32 rows) ----
#pragma unroll
    for (int mt = 0; mt < 2; ++mt) {
      float tmax[4], tsum[4];
#pragma unroll
      for (int r = 0; r < 4; ++r)
        tmax[r] = fmaxf(fmaxf(sc[mt][0][r], sc[mt][1][r]), fmaxf(sc[mt][2][r], sc[mt][3][r]));
#pragma unroll
      for (int d = 1; d < 16; d <<= 1)
#pragma unroll
        for (int r = 0; r < 4; ++r)
          tmax[r] = fmaxf(tmax[r], __shfl_xor(tmax[r], d));

      float mnew[4], alpha[4];
#pragma unroll
      for (int r = 0; r < 4; ++r) {
        mnew[r] = fmaxf(m_i[mt][r], tmax[r]);
        alpha[r] = exp2f((m_i[mt][r] - mnew[r]) * c1);
        m_i[mt][r] = mnew[r];
        tsum[r] = 0.f;
      }
#pragma unroll
      for (int nt = 0; nt < 4; ++nt)
#pragma unroll
        for (int r = 0; r < 4; ++r) {
          const float p = exp2f((sc[mt][nt][r] - mnew[r]) * c1);
          sc[mt][nt][r] = p;
          tsum[r] += p;
        }
#pragma unroll
      for (int d = 1; d < 16; d <<= 1)
#pragma unroll
        for (int r = 0; r < 4; ++r)
          tsum[r] += __shfl_xor(tsum[r], d);
#pragma unroll
      for (int r = 0; r < 4; ++r)
        l_i[mt][r] = l_i[mt][r] * alpha[r] + tsum[r];
#pragma unroll
      for (int dt = 0; dt < 4; ++dt)
#pragma unroll
        for (int r = 0; r < 4; ++r)
          oacc[mt][dt][r] *= alpha[r];
      // write P (C-layout -> LDS [q][kv], bf16) — wave-private rows
#pragma unroll
      for (int nt = 0; nt < 4; ++nt)
#pragma unroll
        for (int r = 0; r < 4; ++r)
          Ps[(w * 32 + mt * 16 + quad * 4 + r) * 64 + nt * 16 + l16] =
              __float2bfloat16(sc[mt][nt][r]);
    }

    // ---- PV: O += P @ V ----
#pragma unroll
    for (int ks = 0; ks < 2; ++ks) {
      bf16x8 pf[2], vf[4];
#pragma unroll
      for (int mt = 0; mt < 2; ++mt)
        pf[mt] = *(const bf16x8*)&Ps[(w * 32 + mt * 16 + l16) * 64 + ks * 32 + quad * 8];
#pragma unroll
      for (int dt = 0; dt < 4; ++dt)
        vf[dt] = *(const bf16x8*)&VTs[(dt * 16 + l16) * 64 + ks * 32 + quad * 8];
#pragma unroll
      for (int mt = 0; mt < 2; ++mt)
#pragma unroll
        for (int dt = 0; dt < 4; ++dt)
          oacc[mt][dt] = MFMA_BF16(pf[mt], vf[dt], oacc[mt][dt]);
    }
  }

  // epilogue: O = oacc / l
#pragma unroll
  for (int mt = 0; mt < 2; ++mt) {
    float inv[4];
#pragma unroll
    for (int r = 0; r < 4; ++r) inv[r] = 1.0f / l_i[mt][r];
#pragma unroll
    for (int dt = 0; dt < 4; ++dt)
#pragma unroll
      for (int r = 0; r < 4; ++r)
        O[(size_t)(b * S + q0 + w * 32 + mt * 16 + quad * 4 + r) * HID + h * HD + dt * 16 + l16] =
            __float2bfloat16(oacc[mt][dt][r] * inv[r]);
  }
}

extern "C" void kernel_launch(void* const* d_in, const int* in_sizes, int n_in,
                              void* d_out, int out_size, void* d_ws, size_t ws_size,
                              hipStream_t stream) {
  const float* hidden = (const float*)d_in[0];
  const float* Wq = (const float*)d_in[1];
  const float* bq = (const float*)d_in[2];
  const float* Wk = (const float*)d_in[3];
  const float* bk = (const float*)d_in[4];
  const float* Wv = (const float*)d_in[5];
  const float* bv = (const float*)d_in[6];
  const float* Wo = (const float*)d_in[7];
  const float* bo = (const float*)d_in[8];
  float* out = (float*)d_out;

  constexpr int B = 2, S = 2048, HID = 2048, NH = 32, KV = 512;
  constexpr int M = B * S;  // 4096

  char* ws = (char*)d_ws;
  bf16_t* hiddenB = (bf16_t*)ws; ws += (size_t)M * HID * 2;
  bf16_t* WqT = (bf16_t*)ws;     ws += (size_t)HID * HID * 2;
  bf16_t* WkT = (bf16_t*)ws;     ws += (size_t)KV * HID * 2;
  bf16_t* WvT = (bf16_t*)ws;     ws += (size_t)KV * HID * 2;
  bf16_t* WoT = (bf16_t*)ws;     ws += (size_t)HID * HID * 2;
  bf16_t* q = (bf16_t*)ws;       ws += (size_t)M * HID * 2;
  bf16_t* k = (bf16_t*)ws;       ws += (size_t)M * KV * 2;
  bf16_t* v = (bf16_t*)ws;       ws += (size_t)M * KV * 2;
  bf16_t* vT = (bf16_t*)ws;      ws += (size_t)M * KV * 2;
  bf16_t* attn = (bf16_t*)ws;    ws += (size_t)M * HID * 2;

  dim3 tb(32, 8);
  cast_f32_to_bf16<<<(M * HID / 4 + 255) / 256, 256, 0, stream>>>(hidden, hiddenB, M * HID / 4);
  transpose_to_bf16<float><<<dim3(HID / 32, HID / 32, 1), tb, 0, stream>>>(Wq, WqT, HID, HID);
  transpose_to_bf16<float><<<dim3(KV / 32, HID / 32, 1), tb, 0, stream>>>(Wk, WkT, HID, KV);
  transpose_to_bf16<float><<<dim3(KV / 32, HID / 32, 1), tb, 0, stream>>>(Wv, WvT, HID, KV);
  transpose_to_bf16<float><<<dim3(HID / 32, HID / 32, 1), tb, 0, stream>>>(Wo, WoT, HID, HID);

  gemm_bt<bf16_t><<<dim3(HID / 128, M / 128), 256, 0, stream>>>(hiddenB, WqT, bq, q, M, HID, HID);
  gemm_bt<bf16_t><<<dim3(KV / 128, M / 128), 256, 0, stream>>>(hiddenB, WkT, bk, k, M, KV, HID);
  gemm_bt<bf16_t><<<dim3(KV / 128, M / 128), 256, 0, stream>>>(hiddenB, WvT, bv, v, M, KV, HID);

  // v [b][s][512] -> vT [b][512][s]
  transpose_to_bf16<bf16_t><<<dim3(KV / 32, S / 32, B), tb, 0, stream>>>(v, vT, S, KV);

  gqa_attn<<<dim3(S / 128, NH, B), 256, 0, stream>>>(q, k, vT, attn);

  gemm_bt<float><<<dim3(HID / 128, M / 128), 256, 0, stream>>>(attn, WoT, bo, out, M, HID, HID);
}

// Round 2
// 400.849 us; speedup vs baseline: 1.4944x; 1.4944x over previous
//
#include <hip/hip_runtime.h>
#include <hip/hip_bf16.h>
#include <math.h>

typedef __bf16 bf16x8 __attribute__((ext_vector_type(8)));
typedef float f32x4 __attribute__((ext_vector_type(4)));
typedef __hip_bfloat16 bf16_t;

#define MFMA_BF16(a, b, c) __builtin_amdgcn_mfma_f32_16x16x32_bf16((a), (b), (c), 0, 0, 0)

// async global->LDS, 16B per lane; LDS dest = wave-uniform base + lane*16
__device__ __forceinline__ void async_copy16(const bf16_t* g, bf16_t* lds_base) {
  __builtin_amdgcn_global_load_lds(
      (const __attribute__((address_space(1))) unsigned int*)g,
      (__attribute__((address_space(3))) unsigned int*)lds_base,
      16, 0, 0);
}

__device__ __forceinline__ unsigned short f2bfu(float x) {
  union { bf16_t b; unsigned short u; } cv;
  cv.b = __float2bfloat16(x);
  return cv.u;
}

// ---------------- cast f32 -> bf16 (vectorized) ----------------
__global__ void cast_f32_to_bf16(const float* __restrict__ in, bf16_t* __restrict__ out, int n4) {
  int i = blockIdx.x * blockDim.x + threadIdx.x;
  if (i < n4) {
    float4 v = ((const float4*)in)[i];
    union { bf16_t h[4]; ushort4 u; } cv;
    cv.h[0] = __float2bfloat16(v.x);
    cv.h[1] = __float2bfloat16(v.y);
    cv.h[2] = __float2bfloat16(v.z);
    cv.h[3] = __float2bfloat16(v.w);
    ((ushort4*)out)[i] = cv.u;
  }
}

__global__ void concat_bias(const float* __restrict__ bk, const float* __restrict__ bv,
                            float* __restrict__ bkv) {
  int i = blockIdx.x * blockDim.x + threadIdx.x;  // 1024 threads
  bkv[i] = (i < 512) ? bk[i] : bv[i - 512];
}

// ---------------- strided transpose + cast -> bf16 ----------------
// logical in element (z, r, c) at in[z*in_bs + r*in_rs + c]; out (z, c, r) at out[z*out_bs + c*R + r]
template <typename TIN>
__global__ void transpose_to_bf16(const TIN* __restrict__ in, bf16_t* __restrict__ out,
                                  int R, int C, int in_rs, size_t in_bs, size_t out_bs) {
  __shared__ float tile[32][33];
  in += (size_t)blockIdx.z * in_bs;
  out += (size_t)blockIdx.z * out_bs;
  const int c0 = blockIdx.x * 32, r0 = blockIdx.y * 32;
  const int tx = threadIdx.x, ty = threadIdx.y;
#pragma unroll
  for (int i = ty; i < 32; i += 8)
    tile[i][tx] = (float)in[(size_t)(r0 + i) * in_rs + c0 + tx];
  __syncthreads();
#pragma unroll
  for (int i = ty; i < 32; i += 8)
    out[(size_t)(c0 + i) * R + r0 + tx] = __float2bfloat16(tile[tx][i]);
}

// ---------------- GEMM: C[M,N] = A[M,K] @ Bt[N,K]^T + bias ----------------
template <typename TOUT>
__global__ __launch_bounds__(256, 2) void gemm_bt(
    const bf16_t* __restrict__ A, const bf16_t* __restrict__ Bt,
    const float* __restrict__ bias, TOUT* __restrict__ C,
    int M, int N, int K) {
  __shared__ alignas(16) bf16_t As[128 * 32];
  __shared__ alignas(16) bf16_t Bs[128 * 32];

  const int tid = threadIdx.x;
  const int w = tid >> 6, lane = tid & 63;
  const int quad = lane >> 4, l16 = lane & 15;
  const int wm = w >> 1, wn = w & 1;
  const int m0 = blockIdx.y * 128, n0 = blockIdx.x * 128;

  f32x4 acc[4][4] = {};

  const int srow = lane >> 2;        // 0..15 within a 16-row chunk
  const int scol = (lane & 3) * 8;   // bf16 col offset (16B chunks)

  for (int k0 = 0; k0 < K; k0 += 32) {
#pragma unroll
    for (int c = 0; c < 2; ++c) {
      const int r = w * 32 + c * 16 + srow;
      async_copy16(A + (size_t)(m0 + r) * K + k0 + scol, &As[(w * 32 + c * 16) * 32]);
      async_copy16(Bt + (size_t)(n0 + r) * K + k0 + scol, &Bs[(w * 32 + c * 16) * 32]);
    }
    __syncthreads();

    bf16x8 af[4], bf[4];
#pragma unroll
    for (int i = 0; i < 4; ++i) {
      af[i] = *(const bf16x8*)&As[(wm * 64 + i * 16 + l16) * 32 + quad * 8];
      bf[i] = *(const bf16x8*)&Bs[(wn * 64 + i * 16 + l16) * 32 + quad * 8];
    }
#pragma unroll
    for (int i = 0; i < 4; ++i)
#pragma unroll
      for (int j = 0; j < 4; ++j)
        acc[i][j] = MFMA_BF16(af[i], bf[j], acc[i][j]);
    __syncthreads();
  }

#pragma unroll
  for (int i = 0; i < 4; ++i) {
    const int row = m0 + wm * 64 + i * 16 + quad * 4;
#pragma unroll
    for (int j = 0; j < 4; ++j) {
      const int col = n0 + wn * 64 + j * 16 + l16;
      const float bv = bias[col];
#pragma unroll
      for (int r = 0; r < 4; ++r) {
        const float val = acc[i][j][r] + bv;
        if constexpr (__is_same(TOUT, float)) {
          C[(size_t)(row + r) * N + col] = val;
        } else {
          C[(size_t)(row + r) * N + col] = __float2bfloat16(val);
        }
      }
    }
  }
}

// ---------------- GQA flash attention (v2: swizzled LDS, S^T orientation) ----------------
// Q: [B*S][2048] bf16; Kd: [B*S][1024] (k at col g*64, row stride 1024)
// VT: [B*512][2048] bf16 (row b*512+g*64+d, col s); O: [B*S][2048] bf16
// grid (S/128, NH, B), 256 threads; wave owns 32 q rows.
// All LDS tiles: 64-elem rows (128B), 16B chunks XOR-swizzled: phys = chunk ^ (row&7).
__global__ __launch_bounds__(256, 3) void gqa_attn(
    const bf16_t* __restrict__ Q, const bf16_t* __restrict__ Kd,
    const bf16_t* __restrict__ VT, bf16_t* __restrict__ O) {
  constexpr int S = 2048, HID = 2048, KVS = 1024, HD = 64;
  const int tid = threadIdx.x;
  const int w = tid >> 6, lane = tid & 63;
  const int quad = lane >> 4, l16 = lane & 15;
  const int q0 = blockIdx.x * 128;
  const int h = blockIdx.y, b = blockIdx.z;
  const int g = h >> 2;  // rep = 4

  __shared__ alignas(16) bf16_t Ks[64 * 64];
  __shared__ alignas(16) bf16_t VTs[64 * 64];
  __shared__ alignas(16) bf16_t Ps[128 * 64];

  const float c1 = 0.125f * 1.44269504089f;  // scale * log2(e), folded into Q

  // Q fragments in registers (B-operand layout: n=l16, k=quad*8+j), pre-scaled by c1
  bf16x8 qf[2][2];
#pragma unroll
  for (int mt = 0; mt < 2; ++mt)
#pragma unroll
    for (int ks = 0; ks < 2; ++ks) {
      bf16x8 t = *(const bf16x8*)&Q[(size_t)(b * S + q0 + w * 32 + mt * 16 + l16) * HID +
                                    h * HD + ks * 32 + quad * 8];
#pragma unroll
      for (int j = 0; j < 8; ++j) t[j] = (__bf16)((float)t[j] * c1);
      qf[mt][ks] = t;
    }

  const int rr = lane >> 3, c7 = lane & 7;
  const int scol = (c7 ^ rr) * 8;  // swizzled SOURCE column so LDS dest lands swizzled
  const int sx = l16 & 7;          // row&7 for fragment rows

  const bf16_t* Kbase = Kd + (size_t)b * S * KVS + g * HD;
  const bf16_t* Vbase = VT + (size_t)(b * 512 + g * HD) * S;

  float lsum[2] = {0.f, 0.f};
  f32x4 oacc[2][4] = {};

  for (int s0 = 0; s0 < S; s0 += 64) {
    __syncthreads();
#pragma unroll
    for (int cg = 0; cg < 2; ++cg) {
      const int r = w * 16 + cg * 8 + rr;
      async_copy16(Kbase + (size_t)(s0 + r) * KVS + scol, &Ks[(w * 16 + cg * 8) * 64]);
      async_copy16(Vbase + (size_t)r * S + s0 + scol, &VTs[(w * 16 + cg * 8) * 64]);
    }
    __syncthreads();

    // ---- S^T = K·Q^T (row=kv=quad*4+r, col=q=l16); p=exp2(s); pack -> Ps[q][kv] ----
#pragma unroll
    for (int nt = 0; nt < 4; ++nt) {
      bf16x8 kf0 = *(const bf16x8*)&Ks[(nt * 16 + l16) * 64 + ((quad ^ sx) * 8)];
      bf16x8 kf1 = *(const bf16x8*)&Ks[(nt * 16 + l16) * 64 + (((4 + quad) ^ sx) * 8)];
#pragma unroll
      for (int mt = 0; mt < 2; ++mt) {
        f32x4 s = {};
        s = MFMA_BF16(kf0, qf[mt][0], s);
        s = MFMA_BF16(kf1, qf[mt][1], s);
        const float p0 = exp2f(s[0]), p1 = exp2f(s[1]), p2 = exp2f(s[2]), p3 = exp2f(s[3]);
        lsum[mt] += (p0 + p1) + (p2 + p3);
        ushort4 pk = {f2bfu(p0), f2bfu(p1), f2bfu(p2), f2bfu(p3)};
        // logical col = nt*16 + quad*4 (+r): chunk = nt*2+(quad>>1), in-chunk = (quad&1)*4
        *(ushort4*)&Ps[(w * 32 + mt * 16 + l16) * 64 +
                       (((nt * 2 + (quad >> 1)) ^ sx) * 8) + (quad & 1) * 4] = pk;
      }
    }

    // ---- O += P · V (A = Ps[q][kv], B = VTs -> n=d) ----
#pragma unroll
    for (int kc = 0; kc < 2; ++kc) {
      bf16x8 pf[2];
#pragma unroll
      for (int mt = 0; mt < 2; ++mt)
        pf[mt] = *(const bf16x8*)&Ps[(w * 32 + mt * 16 + l16) * 64 + (((kc * 4 + quad) ^ sx) * 8)];
#pragma unroll
      for (int dt = 0; dt < 4; ++dt) {
        bf16x8 vf = *(const bf16x8*)&VTs[(dt * 16 + l16) * 64 + (((kc * 4 + quad) ^ sx) * 8)];
#pragma unroll
        for (int mt = 0; mt < 2; ++mt)
          oacc[mt][dt] = MFMA_BF16(pf[mt], vf, oacc[mt][dt]);
      }
    }
  }

  // ---- normalize + store (oacc: row q = quad*4+r, col d = l16 within tiles) ----
#pragma unroll
  for (int mt = 0; mt < 2; ++mt) {
    float ls = lsum[mt];  // partial for q = mt*16+l16 over this lane's kv slice
    ls += __shfl_xor(ls, 16);
    ls += __shfl_xor(ls, 32);
    const float iv = 1.0f / ls;
    float linv[4];
#pragma unroll
    for (int r = 0; r < 4; ++r)
      linv[r] = __shfl(iv, (lane & 48) | (quad * 4 + r));  // lane holding q=mt*16+quad*4+r
#pragma unroll
    for (int dt = 0; dt < 4; ++dt)
#pragma unroll
      for (int r = 0; r < 4; ++r)
        O[(size_t)(b * S + q0 + w * 32 + mt * 16 + quad * 4 + r) * HID + h * HD + dt * 16 + l16] =
            __float2bfloat16(oacc[mt][dt][r] * linv[r]);
  }
}

extern "C" void kernel_launch(void* const* d_in, const int* in_sizes, int n_in,
                              void* d_out, int out_size, void* d_ws, size_t ws_size,
                              hipStream_t stream) {
  const float* hidden = (const float*)d_in[0];
  const float* Wq = (const float*)d_in[1];
  const float* bq = (const float*)d_in[2];
  const float* Wk = (const float*)d_in[3];
  const float* bk = (const float*)d_in[4];
  const float* Wv = (const float*)d_in[5];
  const float* bv = (const float*)d_in[6];
  const float* Wo = (const float*)d_in[7];
  const float* bo = (const float*)d_in[8];
  float* out = (float*)d_out;

  constexpr int B = 2, S = 2048, HID = 2048, NH = 32, KV = 512;
  constexpr int M = B * S;  // 4096

  char* ws = (char*)d_ws;
  bf16_t* hiddenB = (bf16_t*)ws; ws += (size_t)M * HID * 2;
  bf16_t* WqT = (bf16_t*)ws;     ws += (size_t)HID * HID * 2;
  bf16_t* WkvT = (bf16_t*)ws;    ws += (size_t)2 * KV * HID * 2;
  bf16_t* WoT = (bf16_t*)ws;     ws += (size_t)HID * HID * 2;
  bf16_t* q = (bf16_t*)ws;       ws += (size_t)M * HID * 2;
  bf16_t* kv = (bf16_t*)ws;      ws += (size_t)M * 2 * KV * 2;
  bf16_t* vT = (bf16_t*)ws;      ws += (size_t)M * KV * 2;
  bf16_t* attn = (bf16_t*)ws;    ws += (size_t)M * HID * 2;
  float* bkv = (float*)ws;       ws += 1024 * 4;

  dim3 tb(32, 8);
  cast_f32_to_bf16<<<(M * HID / 4 + 255) / 256, 256, 0, stream>>>(hidden, hiddenB, M * HID / 4);
  transpose_to_bf16<float><<<dim3(64, 64, 1), tb, 0, stream>>>(Wq, WqT, HID, HID, HID, 0, 0);
  transpose_to_bf16<float><<<dim3(16, 64, 1), tb, 0, stream>>>(Wk, WkvT, HID, KV, KV, 0, 0);
  transpose_to_bf16<float><<<dim3(16, 64, 1), tb, 0, stream>>>(Wv, WkvT + (size_t)KV * HID, HID, KV, KV, 0, 0);
  transpose_to_bf16<float><<<dim3(64, 64, 1), tb, 0, stream>>>(Wo, WoT, HID, HID, HID, 0, 0);
  concat_bias<<<4, 256, 0, stream>>>(bk, bv, bkv);

  gemm_bt<bf16_t><<<dim3(HID / 128, M / 128), 256, 0, stream>>>(hiddenB, WqT, bq, q, M, HID, HID);
  gemm_bt<bf16_t><<<dim3(2 * KV / 128, M / 128), 256, 0, stream>>>(hiddenB, WkvT, bkv, kv, M, 2 * KV, HID);

  // v = kv[:, 512:1024]: [b][s][512] -> vT [b][512][2048]
  transpose_to_bf16<bf16_t><<<dim3(16, 64, 2), tb, 0, stream>>>(
      kv + KV, vT, S, KV, 2 * KV, (size_t)S * 2 * KV, (size_t)KV * S);

  gqa_attn<<<dim3(S / 128, NH, B), 256, 0, stream>>>(q, kv, vT, attn);

  gemm_bt<float><<<dim3(HID / 128, M / 128), 256, 0, stream>>>(attn, WoT, bo, out, M, HID, HID);
}

// Round 3
// 330.754 us; speedup vs baseline: 1.8111x; 1.2119x over previous
//
#include <hip/hip_runtime.h>
#include <hip/hip_bf16.h>
#include <math.h>

typedef __bf16 bf16x8 __attribute__((ext_vector_type(8)));
typedef float f32x4 __attribute__((ext_vector_type(4)));
typedef __hip_bfloat16 bf16_t;

#define MFMA_BF16(a, b, c) __builtin_amdgcn_mfma_f32_16x16x32_bf16((a), (b), (c), 0, 0, 0)

// async global->LDS, 16B per lane; LDS dest = wave-uniform base + lane*16
__device__ __forceinline__ void async_copy16(const bf16_t* g, bf16_t* lds_base) {
  __builtin_amdgcn_global_load_lds(
      (const __attribute__((address_space(1))) unsigned int*)g,
      (__attribute__((address_space(3))) unsigned int*)lds_base,
      16, 0, 0);
}

__device__ __forceinline__ unsigned fbits(float x) { return __builtin_bit_cast(unsigned, x); }

// ---------------- cast f32 -> bf16 (vectorized) ----------------
__global__ void cast_f32_to_bf16(const float* __restrict__ in, bf16_t* __restrict__ out, int n4) {
  int i = blockIdx.x * blockDim.x + threadIdx.x;
  if (i < n4) {
    float4 v = ((const float4*)in)[i];
    union { bf16_t h[4]; ushort4 u; } cv;
    cv.h[0] = __float2bfloat16(v.x);
    cv.h[1] = __float2bfloat16(v.y);
    cv.h[2] = __float2bfloat16(v.z);
    cv.h[3] = __float2bfloat16(v.w);
    ((ushort4*)out)[i] = cv.u;
  }
}

// bqkv[3072] = {bq*qscale (2048), bk (512), bv (512)}
__global__ void concat_bias3(const float* __restrict__ bq, const float* __restrict__ bk,
                             const float* __restrict__ bv, float* __restrict__ dst, float qscale) {
  int i = blockIdx.x * blockDim.x + threadIdx.x;  // 3072
  float v;
  if (i < 2048) v = bq[i] * qscale;
  else if (i < 2560) v = bk[i - 2048];
  else v = bv[i - 2560];
  dst[i] = v;
}

// ---------------- strided transpose + cast -> bf16 (with scale) ----------------
// in (z,r,c) at in[z*in_bs + r*in_rs + c] -> out (z,c,r) at out[z*out_bs + c*R + r]
template <typename TIN>
__global__ void transpose_to_bf16(const TIN* __restrict__ in, bf16_t* __restrict__ out,
                                  int R, int C, int in_rs, size_t in_bs, size_t out_bs,
                                  float scale) {
  __shared__ float tile[32][33];
  in += (size_t)blockIdx.z * in_bs;
  out += (size_t)blockIdx.z * out_bs;
  const int c0 = blockIdx.x * 32, r0 = blockIdx.y * 32;
  const int tx = threadIdx.x, ty = threadIdx.y;
#pragma unroll
  for (int i = ty; i < 32; i += 8)
    tile[i][tx] = (float)in[(size_t)(r0 + i) * in_rs + c0 + tx];
  __syncthreads();
#pragma unroll
  for (int i = ty; i < 32; i += 8)
    out[(size_t)(c0 + i) * R + r0 + tx] = __float2bfloat16(tile[tx][i] * scale);
}

// ---------------- GEMM: C[M,N] = A[M,K] @ Bt[N,K]^T + bias ----------------
template <typename TOUT>
__global__ __launch_bounds__(256, 2) void gemm_bt(
    const bf16_t* __restrict__ A, const bf16_t* __restrict__ Bt,
    const float* __restrict__ bias, TOUT* __restrict__ C,
    int M, int N, int K) {
  __shared__ alignas(16) bf16_t As[128 * 32];
  __shared__ alignas(16) bf16_t Bs[128 * 32];

  const int tid = threadIdx.x;
  const int w = tid >> 6, lane = tid & 63;
  const int quad = lane >> 4, l16 = lane & 15;
  const int wm = w >> 1, wn = w & 1;
  const int m0 = blockIdx.y * 128, n0 = blockIdx.x * 128;

  f32x4 acc[4][4] = {};

  const int srow = lane >> 2;
  const int scol = (lane & 3) * 8;

  for (int k0 = 0; k0 < K; k0 += 32) {
#pragma unroll
    for (int c = 0; c < 2; ++c) {
      const int r = w * 32 + c * 16 + srow;
      async_copy16(A + (size_t)(m0 + r) * K + k0 + scol, &As[(w * 32 + c * 16) * 32]);
      async_copy16(Bt + (size_t)(n0 + r) * K + k0 + scol, &Bs[(w * 32 + c * 16) * 32]);
    }
    __syncthreads();

    bf16x8 af[4], bf[4];
#pragma unroll
    for (int i = 0; i < 4; ++i) {
      af[i] = *(const bf16x8*)&As[(wm * 64 + i * 16 + l16) * 32 + quad * 8];
      bf[i] = *(const bf16x8*)&Bs[(wn * 64 + i * 16 + l16) * 32 + quad * 8];
    }
#pragma unroll
    for (int i = 0; i < 4; ++i)
#pragma unroll
      for (int j = 0; j < 4; ++j)
        acc[i][j] = MFMA_BF16(af[i], bf[j], acc[i][j]);
    __syncthreads();
  }

#pragma unroll
  for (int i = 0; i < 4; ++i) {
    const int row = m0 + wm * 64 + i * 16 + quad * 4;
#pragma unroll
    for (int j = 0; j < 4; ++j) {
      const int col = n0 + wn * 64 + j * 16 + l16;
      const float bv = bias[col];
#pragma unroll
      for (int r = 0; r < 4; ++r) {
        const float val = acc[i][j][r] + bv;
        if constexpr (__is_same(TOUT, float)) {
          C[(size_t)(row + r) * N + col] = val;
        } else {
          C[(size_t)(row + r) * N + col] = __float2bfloat16(val);
        }
      }
    }
  }
}

// ---------------- GQA flash attention (v3: raw exp2, perm-pack, ones-MFMA lsum) ------------
// QKV: [B*S][3072] bf16 (q at col h*64, Wq pre-scaled by 0.125*log2e; k at 2048+g*64; v at 2560+g*64)
// VT: [B*512][2048] bf16 (row b*512+g*64+d, col s); O: [B*S][2048] bf16
// grid (S/128, NH, B), 256 threads; wave owns 32 q rows; 4 blocks/CU (grid == 1024 == 4*256).
// LDS tiles: 64-elem rows, 16B chunks XOR-swizzled: phys_chunk = chunk ^ (row&7).
__global__ __launch_bounds__(256, 4) void gqa_attn(
    const bf16_t* __restrict__ QKV, const bf16_t* __restrict__ VT, bf16_t* __restrict__ O) {
  constexpr int S = 2048, HID = 2048, QKVS = 3072, HD = 64;
  const int tid = threadIdx.x;
  const int w = tid >> 6, lane = tid & 63;
  const int quad = lane >> 4, l16 = lane & 15;
  const int q0 = blockIdx.x * 128;
  const int h = blockIdx.y, b = blockIdx.z;
  const int g = h >> 2;  // rep = 4

  __shared__ alignas(16) bf16_t Ks[64 * 64];
  __shared__ alignas(16) bf16_t VTs[64 * 64];
  __shared__ alignas(16) bf16_t Ps[128 * 64];

  // Q fragments in registers (B-operand layout: n=l16 -> q, k=quad*8+j); already scaled
  bf16x8 qf[2][2];
#pragma unroll
  for (int mt = 0; mt < 2; ++mt)
#pragma unroll
    for (int ks = 0; ks < 2; ++ks)
      qf[mt][ks] = *(const bf16x8*)&QKV[(size_t)(b * S + q0 + w * 32 + mt * 16 + l16) * QKVS +
                                        h * HD + ks * 32 + quad * 8];

  const int rr = lane >> 3, c7 = lane & 7;
  const int scol = (c7 ^ rr) * 8;  // swizzled SOURCE column so LDS dest lands swizzled
  const int sx = l16 & 7;

  const bf16_t* Kbase = QKV + (size_t)b * S * QKVS + 2048 + g * HD;
  const bf16_t* Vbase = VT + (size_t)(b * 512 + g * HD) * S;

  f32x4 oacc[2][4] = {};
  f32x4 lacc[2] = {};
  bf16x8 ones;
#pragma unroll
  for (int j = 0; j < 8; ++j) ones[j] = (__bf16)1.0f;

  for (int s0 = 0; s0 < S; s0 += 64) {
    __syncthreads();
#pragma unroll
    for (int cg = 0; cg < 2; ++cg) {
      const int r = w * 16 + cg * 8 + rr;
      async_copy16(Kbase + (size_t)(s0 + r) * QKVS + scol, &Ks[(w * 16 + cg * 8) * 64]);
      async_copy16(Vbase + (size_t)r * S + s0 + scol, &VTs[(w * 16 + cg * 8) * 64]);
    }
    __syncthreads();

    // ---- S^T = K·Q^T (row=kv=quad*4+r, col=q=l16); p=exp2(s); pack(trunc) -> Ps[q][kv] ----
#pragma unroll
    for (int nt = 0; nt < 4; ++nt) {
      bf16x8 kf0 = *(const bf16x8*)&Ks[(nt * 16 + l16) * 64 + ((quad ^ sx) * 8)];
      bf16x8 kf1 = *(const bf16x8*)&Ks[(nt * 16 + l16) * 64 + (((4 + quad) ^ sx) * 8)];
#pragma unroll
      for (int mt = 0; mt < 2; ++mt) {
        f32x4 s = {};
        s = MFMA_BF16(kf0, qf[mt][0], s);
        s = MFMA_BF16(kf1, qf[mt][1], s);
        const float p0 = __builtin_amdgcn_exp2f(s[0]);
        const float p1 = __builtin_amdgcn_exp2f(s[1]);
        const float p2 = __builtin_amdgcn_exp2f(s[2]);
        const float p3 = __builtin_amdgcn_exp2f(s[3]);
        uint2 pk;
        pk.x = __builtin_amdgcn_perm(fbits(p1), fbits(p0), 0x07060302);  // [bf16(p1)|bf16(p0)]
        pk.y = __builtin_amdgcn_perm(fbits(p3), fbits(p2), 0x07060302);
        // logical col = nt*16 + quad*4 (+r): chunk = nt*2+(quad>>1), in-chunk off = (quad&1)*4
        *(uint2*)&Ps[(w * 32 + mt * 16 + l16) * 64 +
                     (((nt * 2 + (quad >> 1)) ^ sx) * 8) + (quad & 1) * 4] = pk;
      }
    }

    // ---- O += P·V; row-sums via ones-B MFMA (sums the truncated bf16 P -> bias cancels) ----
#pragma unroll
    for (int kc = 0; kc < 2; ++kc) {
      bf16x8 pf[2];
#pragma unroll
      for (int mt = 0; mt < 2; ++mt) {
        pf[mt] = *(const bf16x8*)&Ps[(w * 32 + mt * 16 + l16) * 64 + (((kc * 4 + quad) ^ sx) * 8)];
        lacc[mt] = MFMA_BF16(pf[mt], ones, lacc[mt]);
      }
#pragma unroll
      for (int dt = 0; dt < 4; ++dt) {
        bf16x8 vf = *(const bf16x8*)&VTs[(dt * 16 + l16) * 64 + (((kc * 4 + quad) ^ sx) * 8)];
#pragma unroll
        for (int mt = 0; mt < 2; ++mt)
          oacc[mt][dt] = MFMA_BF16(pf[mt], vf, oacc[mt][dt]);
      }
    }
  }

  // ---- normalize + store; lacc[mt][r] is lsum for q=mt*16+quad*4+r (same row as oacc) ----
#pragma unroll
  for (int mt = 0; mt < 2; ++mt) {
    float linv[4];
#pragma unroll
    for (int r = 0; r < 4; ++r) linv[r] = 1.0f / lacc[mt][r];
#pragma unroll
    for (int dt = 0; dt < 4; ++dt)
#pragma unroll
      for (int r = 0; r < 4; ++r)
        O[(size_t)(b * S + q0 + w * 32 + mt * 16 + quad * 4 + r) * HID + h * HD + dt * 16 + l16] =
            __float2bfloat16(oacc[mt][dt][r] * linv[r]);
  }
}

extern "C" void kernel_launch(void* const* d_in, const int* in_sizes, int n_in,
                              void* d_out, int out_size, void* d_ws, size_t ws_size,
                              hipStream_t stream) {
  const float* hidden = (const float*)d_in[0];
  const float* Wq = (const float*)d_in[1];
  const float* bq = (const float*)d_in[2];
  const float* Wk = (const float*)d_in[3];
  const float* bk = (const float*)d_in[4];
  const float* Wv = (const float*)d_in[5];
  const float* bv = (const float*)d_in[6];
  const float* Wo = (const float*)d_in[7];
  const float* bo = (const float*)d_in[8];
  float* out = (float*)d_out;

  constexpr int B = 2, S = 2048, HID = 2048, KV = 512, QKVN = 3072;
  constexpr int M = B * S;  // 4096
  const float c1 = 0.125f * 1.44269504089f;

  char* ws = (char*)d_ws;
  bf16_t* hiddenB = (bf16_t*)ws; ws += (size_t)M * HID * 2;
  bf16_t* WqkvT = (bf16_t*)ws;   ws += (size_t)QKVN * HID * 2;
  bf16_t* WoT = (bf16_t*)ws;     ws += (size_t)HID * HID * 2;
  bf16_t* qkv = (bf16_t*)ws;     ws += (size_t)M * QKVN * 2;
  bf16_t* vT = (bf16_t*)ws;      ws += (size_t)M * KV * 2;
  bf16_t* attn = (bf16_t*)ws;    ws += (size_t)M * HID * 2;
  float* bqkv = (float*)ws;      ws += QKVN * 4;

  dim3 tb(32, 8);
  cast_f32_to_bf16<<<(M * HID / 4 + 255) / 256, 256, 0, stream>>>(hidden, hiddenB, M * HID / 4);
  // WqkvT rows: [0,2048) = Wq^T * c1, [2048,2560) = Wk^T, [2560,3072) = Wv^T
  transpose_to_bf16<float><<<dim3(64, 64, 1), tb, 0, stream>>>(Wq, WqkvT, HID, HID, HID, 0, 0, c1);
  transpose_to_bf16<float><<<dim3(16, 64, 1), tb, 0, stream>>>(
      Wk, WqkvT + (size_t)2048 * HID, HID, KV, KV, 0, 0, 1.0f);
  transpose_to_bf16<float><<<dim3(16, 64, 1), tb, 0, stream>>>(
      Wv, WqkvT + (size_t)2560 * HID, HID, KV, KV, 0, 0, 1.0f);
  transpose_to_bf16<float><<<dim3(64, 64, 1), tb, 0, stream>>>(Wo, WoT, HID, HID, HID, 0, 0, 1.0f);
  concat_bias3<<<QKVN / 256, 256, 0, stream>>>(bq, bk, bv, bqkv, c1);

  gemm_bt<bf16_t><<<dim3(QKVN / 128, M / 128), 256, 0, stream>>>(hiddenB, WqkvT, bqkv, qkv, M, QKVN, HID);

  // v = qkv[:, 2560:3072]: [b][s][512] -> vT [b][512][2048]
  transpose_to_bf16<bf16_t><<<dim3(16, 64, 2), tb, 0, stream>>>(
      qkv + 2560, vT, S, KV, QKVN, (size_t)S * QKVN, (size_t)KV * S, 1.0f);

  gqa_attn<<<dim3(S / 128, 32, B), 256, 0, stream>>>(qkv, vT, attn);

  gemm_bt<float><<<dim3(HID / 128, M / 128), 256, 0, stream>>>(attn, WoT, bo, out, M, HID, HID);
}